// Round 11
// baseline (193.111 us; speedup 1.0000x reference)
//
#include <hip/hip_runtime.h>
#include <math.h>

#define HDIM 1024
#define INVB (1 << 13)
#define SBIT (1 << 14)
#define OBIT (1 << 15)
#define SLOTS 10   // chunk = 32 compacted rows, capacity 320 adj-rows per b
#define CH 32

// ---------------- K1: self-compacting fused score+exp+V-weight --------------
// grid 64*SLOTS blocks x 256 threads; chunk = 32 compacted adj rows.
// Step 0: block redoes the adj ballot/prefix scan for its b, extracts its own
//         32-row window (codes n|s<<14|o<<15), pads with INVB.
// Phase 1: 4 waves x 8 rows -> e = exp(dot(K,Wk)), write e_out, stage weights.
// Phase 2: wave 0 compacts (s|o)-active rows; stream those V rows 8-deep.
// Tail: last block per b (atomic counter) does denom + u reduce+normalize.
__global__ __launch_bounds__(256) void k_fusedA(const float* __restrict__ Kmat,
                                                const float* __restrict__ V,
                                                const int* __restrict__ adj,
                                                const int* __restrict__ sm,
                                                const int* __restrict__ om,
                                                const float* __restrict__ Wk,
                                                float* __restrict__ e_out,
                                                float* __restrict__ p0,
                                                float* __restrict__ p1,
                                                float* __restrict__ w_out,
                                                float* __restrict__ u0,
                                                float* __restrict__ u1,
                                                int* __restrict__ cntB) {
    __shared__ int segc[8];
    __shared__ int codeL[CH];
    __shared__ float2 eso[CH];
    __shared__ float2 cw[CH + 8];
    __shared__ int cn[CH + 8];
    __shared__ int s_cnz8;
    __shared__ int s_rank;
    __shared__ float red2[4];
    int b = blockIdx.x / SLOTS;
    int chunk = blockIdx.x - b * SLOTS;
    int tid = threadIdx.x, wave = tid >> 6, lane = tid & 63;
    int gb = b * 512;
    int start = chunk * CH;
    size_t pbase = ((size_t)(chunk * 64 + b)) * HDIM + tid * 4;

    // ---- step 0: scan adj for this b -----------------------------------
    int r0w = wave * 128;
    int a0p = adj[gb + r0w + lane] != 0;
    int a1p = adj[gb + r0w + 64 + lane] != 0;
    unsigned long long m0 = __ballot(a0p);
    unsigned long long m1 = __ballot(a1p);
    if (lane == 0) {
        segc[wave * 2]     = __popcll(m0);
        segc[wave * 2 + 1] = __popcll(m1);
    }
    __syncthreads();
    int tot = 0;
#pragma unroll
    for (int i = 0; i < 8; ++i) tot += segc[i];
    int kp = (tot + CH - 1) & ~(CH - 1);
    bool act = (start < kp);

    if (act) {
        // window extraction
        unsigned long long lt = (1ull << lane) - 1ull;
        int base = 0;
#pragma unroll
        for (int i = 0; i < 8; ++i) if (i < wave * 2) base += segc[i];
        int pos0 = base + __popcll(m0 & lt);
        if (a0p && pos0 >= start && pos0 < start + CH) {
            int r = r0w + lane;
            codeL[pos0 - start] = r | (sm[gb + r] ? SBIT : 0) | (om[gb + r] ? OBIT : 0);
        }
        int base1 = base + __popcll(m0);
        int pos1 = base1 + __popcll(m1 & lt);
        if (a1p && pos1 >= start && pos1 < start + CH) {
            int r = r0w + 64 + lane;
            codeL[pos1 - start] = r | (sm[gb + r] ? SBIT : 0) | (om[gb + r] ? OBIT : 0);
        }
        if (tid < CH && start + tid >= tot) codeL[tid] = INVB;
        const float4* wk4 = (const float4*)Wk;
        float4 wk0 = wk4[lane], wk1 = wk4[64 + lane],
               wk2 = wk4[128 + lane], wk3 = wk4[192 + lane];
        __syncthreads();

        // ---- phase 1: 8 rows per wave, two at a time ----------------------
#pragma unroll
        for (int pp = 0; pp < 4; ++pp) {
            int rr = wave * 8 + pp * 2;
            int c0 = codeL[rr], c1 = codeL[rr + 1];
            int n0 = c0 & 511, n1 = c1 & 511;
            const float4* kq0 = (const float4*)(Kmat + (size_t)(gb + n0) * HDIM);
            const float4* kq1 = (const float4*)(Kmat + (size_t)(gb + n1) * HDIM);
            float4 a0 = kq0[lane],       a1 = kq0[64 + lane],
                   a2 = kq0[128 + lane], a3 = kq0[192 + lane];
            float4 d0 = kq1[lane],       d1 = kq1[64 + lane],
                   d2 = kq1[128 + lane], d3 = kq1[192 + lane];
            __builtin_amdgcn_sched_barrier(0);

            float s0 = 0.f, s1 = 0.f;
            s0 = fmaf(a0.x, wk0.x, s0); s0 = fmaf(a0.y, wk0.y, s0);
            s0 = fmaf(a0.z, wk0.z, s0); s0 = fmaf(a0.w, wk0.w, s0);
            s0 = fmaf(a1.x, wk1.x, s0); s0 = fmaf(a1.y, wk1.y, s0);
            s0 = fmaf(a1.z, wk1.z, s0); s0 = fmaf(a1.w, wk1.w, s0);
            s0 = fmaf(a2.x, wk2.x, s0); s0 = fmaf(a2.y, wk2.y, s0);
            s0 = fmaf(a2.z, wk2.z, s0); s0 = fmaf(a2.w, wk2.w, s0);
            s0 = fmaf(a3.x, wk3.x, s0); s0 = fmaf(a3.y, wk3.y, s0);
            s0 = fmaf(a3.z, wk3.z, s0); s0 = fmaf(a3.w, wk3.w, s0);
            s1 = fmaf(d0.x, wk0.x, s1); s1 = fmaf(d0.y, wk0.y, s1);
            s1 = fmaf(d0.z, wk0.z, s1); s1 = fmaf(d0.w, wk0.w, s1);
            s1 = fmaf(d1.x, wk1.x, s1); s1 = fmaf(d1.y, wk1.y, s1);
            s1 = fmaf(d1.z, wk1.z, s1); s1 = fmaf(d1.w, wk1.w, s1);
            s1 = fmaf(d2.x, wk2.x, s1); s1 = fmaf(d2.y, wk2.y, s1);
            s1 = fmaf(d2.z, wk2.z, s1); s1 = fmaf(d2.w, wk2.w, s1);
            s1 = fmaf(d3.x, wk3.x, s1); s1 = fmaf(d3.y, wk3.y, s1);
            s1 = fmaf(d3.z, wk3.z, s1); s1 = fmaf(d3.w, wk3.w, s1);

#pragma unroll
            for (int off = 32; off; off >>= 1) {
                s0 += __shfl_xor(s0, off);
                s1 += __shfl_xor(s1, off);
            }
            if (lane == 0) {
                float e0 = expf(s0), e1 = expf(s1);
                if (!(c0 & INVB)) e_out[gb + n0] = e0;
                if (!(c1 & INVB)) e_out[gb + n1] = e1;
                eso[rr]     = make_float2((c0 & SBIT) ? e0 : 0.f, (c0 & OBIT) ? e0 : 0.f);
                eso[rr + 1] = make_float2((c1 & SBIT) ? e1 : 0.f, (c1 & OBIT) ? e1 : 0.f);
            }
        }
        __syncthreads();

        // ---- compaction of (s|o)-active rows by wave 0 ---------------------
        if (wave == 0) {
            bool pred = (lane < CH) && ((codeL[lane] & (SBIT | OBIT)) != 0) &&
                        !(codeL[lane] & INVB);
            unsigned long long m = __ballot(pred);
            int cnz = __popcll(m);
            if (pred) {
                int pos = __popcll(m & ((1ull << lane) - 1ull));
                cn[pos] = codeL[lane] & 511;
                cw[pos] = eso[lane];
            }
            int cnz8 = (cnz + 7) & ~7;
            if (lane >= CH && lane < CH + 8) {
                int p = cnz + (lane - CH);
                if (p < cnz8) { cn[p] = 0; cw[p] = make_float2(0.f, 0.f); }
            }
            if (lane == 0) s_cnz8 = cnz8;
        }
        __syncthreads();

        // ---- phase 2: V-weight active rows, 8-deep batches -----------------
        int cnz8 = s_cnz8;
        const float* Vb = V + (size_t)gb * HDIM;
        float4 a0 = {0.f, 0.f, 0.f, 0.f};
        float4 a1 = {0.f, 0.f, 0.f, 0.f};
        for (int g = 0; g < cnz8; g += 8) {
            int nn[8]; float2 ww[8];
#pragma unroll
            for (int i = 0; i < 8; ++i) { nn[i] = cn[g + i]; ww[i] = cw[g + i]; }
            float4 v[8];
#pragma unroll
            for (int i = 0; i < 8; ++i)
                v[i] = *((const float4*)(Vb + (size_t)nn[i] * HDIM) + tid);
            __builtin_amdgcn_sched_barrier(0);
#pragma unroll
            for (int i = 0; i < 8; ++i) {
                a0.x = fmaf(ww[i].x, v[i].x, a0.x); a0.y = fmaf(ww[i].x, v[i].y, a0.y);
                a0.z = fmaf(ww[i].x, v[i].z, a0.z); a0.w = fmaf(ww[i].x, v[i].w, a0.w);
                a1.x = fmaf(ww[i].y, v[i].x, a1.x); a1.y = fmaf(ww[i].y, v[i].y, a1.y);
                a1.z = fmaf(ww[i].y, v[i].z, a1.z); a1.w = fmaf(ww[i].y, v[i].w, a1.w);
            }
        }
        *(float4*)(p0 + pbase) = a0;
        *(float4*)(p1 + pbase) = a1;
    } else {
        float4 z = {0.f, 0.f, 0.f, 0.f};
        *(float4*)(p0 + pbase) = z;
        *(float4*)(p1 + pbase) = z;
    }

    // ---- completion: last block for this b does denom + u reduce ----------
    __threadfence();
    if (tid == 0) s_rank = atomicAdd(&cntB[b], 1);
    __syncthreads();
    if (s_rank == SLOTS - 1) {
        __threadfence();
        float ev0 = adj[gb + tid]       ? e_out[gb + tid]       : 0.f;
        float ev1 = adj[gb + 256 + tid] ? e_out[gb + 256 + tid] : 0.f;
        float t = ev0 + ev1;
#pragma unroll
        for (int off = 32; off; off >>= 1) t += __shfl_xor(t, off);
        if (lane == 0) red2[wave] = t;
        __syncthreads();
        float tot2 = red2[0] + red2[1] + red2[2] + red2[3];
        float inv = 1.f / tot2;
        w_out[gb + tid] = ev0 * inv;
        w_out[gb + 256 + tid] = ev1 * inv;

        float4 A = {0.f, 0.f, 0.f, 0.f};
        float4 B = {0.f, 0.f, 0.f, 0.f};
#pragma unroll
        for (int s = 0; s < SLOTS; ++s) {
            size_t o = ((size_t)(s * 64 + b)) * HDIM + tid * 4;
            float4 v0 = *(const float4*)(p0 + o);
            float4 v1 = *(const float4*)(p1 + o);
            A.x += v0.x; A.y += v0.y; A.z += v0.z; A.w += v0.w;
            B.x += v1.x; B.y += v1.y; B.z += v1.z; B.w += v1.w;
        }
        A.x *= inv; A.y *= inv; A.z *= inv; A.w *= inv;
        B.x *= inv; B.y *= inv; B.z *= inv; B.w *= inv;
        *(float4*)(u0 + (size_t)b * HDIM + tid * 4) = A;
        *(float4*)(u1 + (size_t)b * HDIM + tid * 4) = B;
    }
}

// ---------------- K2: split-k GEMM + last-block k-reduction -----------------
// pOut[kc][h][b] partials; last kc-block per ht reduces -> out1[b][h].
// grid 256 blocks (ht*16+kc) x 256 threads. lane=b, wave owns 16 h rows.
__global__ __launch_bounds__(256) void k_out(const float* __restrict__ u0,
                                             const float* __restrict__ u1,
                                             const float* __restrict__ Wr0,
                                             const float* __restrict__ Wr1,
                                             float* __restrict__ pOut,
                                             float* __restrict__ out1,
                                             int* __restrict__ cntH) {
    __shared__ float lds[64 * 128];
    __shared__ int s_rank;
    int tid = threadIdx.x;
    int ht = blockIdx.x >> 4;
    int kc = blockIdx.x & 15;
    const float* usrc = (kc < 8) ? u0 : u1;
    const float* wsrc = (kc < 8) ? Wr0 : Wr1;
    int koff = (kc & 7) * 128;
    int h0 = ht * 64;

    {
        int c4 = tid & 31;
        int r2 = tid >> 5;
#pragma unroll
        for (int i = 0; i < 8; ++i) {
            int row = i * 8 + r2;
            float4 v = *(const float4*)(usrc + (size_t)row * HDIM + koff + c4 * 4);
            *(float4*)&lds[row * 128 + ((c4 ^ (row & 7)) << 2)] = v;
        }
    }
    __syncthreads();

    int b = tid & 63;
    int wu = __builtin_amdgcn_readfirstlane(tid >> 6);
    int hbase = h0 + wu * 16;
    const float* wrow = wsrc + (size_t)hbase * HDIM + koff;

    float acc[16];
#pragma unroll
    for (int j = 0; j < 16; ++j) acc[j] = 0.f;

#pragma unroll 4
    for (int k4 = 0; k4 < 32; ++k4) {
        float4 uv = *(float4*)&lds[b * 128 + ((k4 ^ (b & 7)) << 2)];
#pragma unroll
        for (int j = 0; j < 16; ++j) {
            float4 wv = *(const float4*)(wrow + (size_t)j * HDIM + k4 * 4);
            acc[j] = fmaf(uv.x, wv.x, acc[j]);
            acc[j] = fmaf(uv.y, wv.y, acc[j]);
            acc[j] = fmaf(uv.z, wv.z, acc[j]);
            acc[j] = fmaf(uv.w, wv.w, acc[j]);
        }
    }
#pragma unroll
    for (int j = 0; j < 16; ++j)
        pOut[((size_t)kc * HDIM + hbase + j) * 64 + b] = acc[j];

    // ---- completion: last block for this ht reduces its 64 h rows ----------
    __threadfence();
    if (tid == 0) s_rank = atomicAdd(&cntH[ht], 1);
    __syncthreads();
    if (s_rank == 15) {
        __threadfence();
        int b2 = tid & 63;
        int hl = tid >> 6;
#pragma unroll
        for (int i = 0; i < 16; ++i) {
            int h = h0 + i * 4 + hl;
            float a = 0.f;
#pragma unroll
            for (int c = 0; c < 16; ++c)
                a += pOut[((size_t)c * HDIM + h) * 64 + b2];
            out1[(size_t)b2 * HDIM + h] = a;
        }
    }
}

extern "C" void kernel_launch(void* const* d_in, const int* in_sizes, int n_in,
                              void* d_out, int out_size, void* d_ws, size_t ws_size,
                              hipStream_t stream) {
    const float* Kmat  = (const float*)d_in[1];
    const float* V     = (const float*)d_in[2];
    const int*   adj   = (const int*)d_in[3];
    const int*   smask = (const int*)d_in[4];
    const int*   omask = (const int*)d_in[5];
    const float* Watt  = (const float*)d_in[6];
    const float* Wr0   = (const float*)d_in[8];
    const float* Wr1   = (const float*)d_in[9];
    float* out = (float*)d_out;
    float* ws  = (float*)d_ws;

    // ws layout (float offsets)
    float* e    = ws;                    //  64*512           = 32768
    int*   cnt  = (int*)(ws + 32768);    //  64 + 16 counters (pad 128)
    float* p0   = ws + 32896;            //  SLOTS*64*1024    = 655360
    float* p1   = ws + 688256;           //  SLOTS*64*1024    = 655360
    float* u0   = ws + 1343616;          //  64*1024          = 65536
    float* u1   = ws + 1409152;          //  64*1024          = 65536
    float* pOut = ws + 1474688;          //  16*1024*64       = 1048576
    const float* Wk = Watt + HDIM;       // second half of W_att
    float* out1 = out + 32768;

    hipMemsetAsync(cnt, 0, 80 * sizeof(int), stream);
    k_fusedA<<<64 * SLOTS, 256, 0, stream>>>(Kmat, V, adj, smask, omask, Wk,
                                             e, p0, p1, out, u0, u1, cnt);
    k_out   <<<       256, 256, 0, stream>>>(u0, u1, Wr0, Wr1, pOut, out1, cnt + 64);
}

// Round 12
// 63.451 us; speedup vs baseline: 3.0435x; 3.0435x over previous
//
#include <hip/hip_runtime.h>
#include <math.h>

#define HDIM 1024
#define INVB (1 << 13)
#define SBIT (1 << 14)
#define OBIT (1 << 15)
#define SLOTS 10   // chunk = 32 compacted rows, capacity 320 adj-rows per b
#define CH 32

// ---------------- K1: self-compacting fused score+exp+V-weight --------------
// grid 64*SLOTS blocks x 256 threads; chunk = 32 compacted adj rows.
// Step 0: block redoes the adj ballot/prefix scan for its b (6 KB, L2-hot),
//         extracts its own 32-row window (codes n|s<<14|o<<15), pads w/ INVB.
// Phase 1: 4 waves x 8 rows -> e = exp(dot(K,Wk)), write e_out, stage weights.
// Phase 2: wave 0 compacts (s|o)-active rows; stream those V rows 8-deep.
// NO cross-block atomics/fences (r9/r11 lesson: they cost 25x a launch).
__global__ __launch_bounds__(256) void k_fusedA(const float* __restrict__ Kmat,
                                                const float* __restrict__ V,
                                                const int* __restrict__ adj,
                                                const int* __restrict__ sm,
                                                const int* __restrict__ om,
                                                const float* __restrict__ Wk,
                                                float* __restrict__ e_out,
                                                float* __restrict__ p0,
                                                float* __restrict__ p1) {
    __shared__ int segc[8];
    __shared__ int codeL[CH];
    __shared__ float2 eso[CH];
    __shared__ float2 cw[CH + 8];
    __shared__ int cn[CH + 8];
    __shared__ int s_cnz8;
    int b = blockIdx.x / SLOTS;
    int chunk = blockIdx.x - b * SLOTS;
    int tid = threadIdx.x, wave = tid >> 6, lane = tid & 63;
    int gb = b * 512;
    int start = chunk * CH;
    size_t pbase = ((size_t)(chunk * 64 + b)) * HDIM + tid * 4;

    // ---- step 0: scan adj for this b, pick our window ----------------------
    int r0w = wave * 128;
    int a0p = adj[gb + r0w + lane] != 0;
    int a1p = adj[gb + r0w + 64 + lane] != 0;
    unsigned long long m0 = __ballot(a0p);
    unsigned long long m1 = __ballot(a1p);
    if (lane == 0) {
        segc[wave * 2]     = __popcll(m0);
        segc[wave * 2 + 1] = __popcll(m1);
    }
    __syncthreads();
    int tot = 0;
#pragma unroll
    for (int i = 0; i < 8; ++i) tot += segc[i];
    int kp = (tot + CH - 1) & ~(CH - 1);
    if (start >= kp) {                      // inactive slot: zero the partial
        float4 z = {0.f, 0.f, 0.f, 0.f};
        *(float4*)(p0 + pbase) = z;
        *(float4*)(p1 + pbase) = z;
        return;
    }
    {
        unsigned long long lt = (1ull << lane) - 1ull;
        int base = 0;
#pragma unroll
        for (int i = 0; i < 8; ++i) if (i < wave * 2) base += segc[i];
        int pos0 = base + __popcll(m0 & lt);
        if (a0p && pos0 >= start && pos0 < start + CH) {
            int r = r0w + lane;
            codeL[pos0 - start] = r | (sm[gb + r] ? SBIT : 0) | (om[gb + r] ? OBIT : 0);
        }
        int base1 = base + __popcll(m0);
        int pos1 = base1 + __popcll(m1 & lt);
        if (a1p && pos1 >= start && pos1 < start + CH) {
            int r = r0w + 64 + lane;
            codeL[pos1 - start] = r | (sm[gb + r] ? SBIT : 0) | (om[gb + r] ? OBIT : 0);
        }
    }
    if (tid < CH && start + tid >= tot) codeL[tid] = INVB;
    const float4* wk4 = (const float4*)Wk;
    float4 wk0 = wk4[lane], wk1 = wk4[64 + lane],
           wk2 = wk4[128 + lane], wk3 = wk4[192 + lane];
    __syncthreads();

    // ---- phase 1: 8 rows per wave, two at a time, 8 loads in flight --------
#pragma unroll
    for (int pp = 0; pp < 4; ++pp) {
        int rr = wave * 8 + pp * 2;
        int c0 = codeL[rr], c1 = codeL[rr + 1];
        int n0 = c0 & 511, n1 = c1 & 511;
        const float4* kq0 = (const float4*)(Kmat + (size_t)(gb + n0) * HDIM);
        const float4* kq1 = (const float4*)(Kmat + (size_t)(gb + n1) * HDIM);
        float4 a0 = kq0[lane],       a1 = kq0[64 + lane],
               a2 = kq0[128 + lane], a3 = kq0[192 + lane];
        float4 d0 = kq1[lane],       d1 = kq1[64 + lane],
               d2 = kq1[128 + lane], d3 = kq1[192 + lane];
        __builtin_amdgcn_sched_barrier(0);

        float s0 = 0.f, s1 = 0.f;
        s0 = fmaf(a0.x, wk0.x, s0); s0 = fmaf(a0.y, wk0.y, s0);
        s0 = fmaf(a0.z, wk0.z, s0); s0 = fmaf(a0.w, wk0.w, s0);
        s0 = fmaf(a1.x, wk1.x, s0); s0 = fmaf(a1.y, wk1.y, s0);
        s0 = fmaf(a1.z, wk1.z, s0); s0 = fmaf(a1.w, wk1.w, s0);
        s0 = fmaf(a2.x, wk2.x, s0); s0 = fmaf(a2.y, wk2.y, s0);
        s0 = fmaf(a2.z, wk2.z, s0); s0 = fmaf(a2.w, wk2.w, s0);
        s0 = fmaf(a3.x, wk3.x, s0); s0 = fmaf(a3.y, wk3.y, s0);
        s0 = fmaf(a3.z, wk3.z, s0); s0 = fmaf(a3.w, wk3.w, s0);
        s1 = fmaf(d0.x, wk0.x, s1); s1 = fmaf(d0.y, wk0.y, s1);
        s1 = fmaf(d0.z, wk0.z, s1); s1 = fmaf(d0.w, wk0.w, s1);
        s1 = fmaf(d1.x, wk1.x, s1); s1 = fmaf(d1.y, wk1.y, s1);
        s1 = fmaf(d1.z, wk1.z, s1); s1 = fmaf(d1.w, wk1.w, s1);
        s1 = fmaf(d2.x, wk2.x, s1); s1 = fmaf(d2.y, wk2.y, s1);
        s1 = fmaf(d2.z, wk2.z, s1); s1 = fmaf(d2.w, wk2.w, s1);
        s1 = fmaf(d3.x, wk3.x, s1); s1 = fmaf(d3.y, wk3.y, s1);
        s1 = fmaf(d3.z, wk3.z, s1); s1 = fmaf(d3.w, wk3.w, s1);

#pragma unroll
        for (int off = 32; off; off >>= 1) {
            s0 += __shfl_xor(s0, off);
            s1 += __shfl_xor(s1, off);
        }
        if (lane == 0) {
            float e0 = expf(s0), e1 = expf(s1);
            if (!(c0 & INVB)) e_out[gb + n0] = e0;
            if (!(c1 & INVB)) e_out[gb + n1] = e1;
            eso[rr]     = make_float2((c0 & SBIT) ? e0 : 0.f, (c0 & OBIT) ? e0 : 0.f);
            eso[rr + 1] = make_float2((c1 & SBIT) ? e1 : 0.f, (c1 & OBIT) ? e1 : 0.f);
        }
    }
    __syncthreads();

    // ---- compaction of (s|o)-active rows by wave 0 -------------------------
    if (wave == 0) {
        bool pred = (lane < CH) && ((codeL[lane] & (SBIT | OBIT)) != 0) &&
                    !(codeL[lane] & INVB);
        unsigned long long m = __ballot(pred);
        int cnz = __popcll(m);
        if (pred) {
            int pos = __popcll(m & ((1ull << lane) - 1ull));
            cn[pos] = codeL[lane] & 511;
            cw[pos] = eso[lane];
        }
        int cnz8 = (cnz + 7) & ~7;
        if (lane >= CH && lane < CH + 8) {
            int p = cnz + (lane - CH);
            if (p < cnz8) { cn[p] = 0; cw[p] = make_float2(0.f, 0.f); }
        }
        if (lane == 0) s_cnz8 = cnz8;
    }
    __syncthreads();

    // ---- phase 2: V-weight active rows, 8-deep batches ---------------------
    int cnz8 = s_cnz8;
    const float* Vb = V + (size_t)gb * HDIM;
    float4 a0 = {0.f, 0.f, 0.f, 0.f};
    float4 a1 = {0.f, 0.f, 0.f, 0.f};
    for (int g = 0; g < cnz8; g += 8) {
        int nn[8]; float2 ww[8];
#pragma unroll
        for (int i = 0; i < 8; ++i) { nn[i] = cn[g + i]; ww[i] = cw[g + i]; }
        float4 v[8];
#pragma unroll
        for (int i = 0; i < 8; ++i)
            v[i] = *((const float4*)(Vb + (size_t)nn[i] * HDIM) + tid);
        __builtin_amdgcn_sched_barrier(0);
#pragma unroll
        for (int i = 0; i < 8; ++i) {
            a0.x = fmaf(ww[i].x, v[i].x, a0.x); a0.y = fmaf(ww[i].x, v[i].y, a0.y);
            a0.z = fmaf(ww[i].x, v[i].z, a0.z); a0.w = fmaf(ww[i].x, v[i].w, a0.w);
            a1.x = fmaf(ww[i].y, v[i].x, a1.x); a1.y = fmaf(ww[i].y, v[i].y, a1.y);
            a1.z = fmaf(ww[i].y, v[i].z, a1.z); a1.w = fmaf(ww[i].y, v[i].w, a1.w);
        }
    }
    *(float4*)(p0 + pbase) = a0;
    *(float4*)(p1 + pbase) = a1;
}

// ---------------- K2: denom + attn_weight + u reduce+normalize --------------
// grid 64 blocks (per b) x 512 threads.
__global__ __launch_bounds__(512) void k_denomredu(const float* __restrict__ e,
                                                   const int* __restrict__ adj,
                                                   const float* __restrict__ p0,
                                                   const float* __restrict__ p1,
                                                   float* __restrict__ w_out,
                                                   float* __restrict__ u0,
                                                   float* __restrict__ u1) {
    __shared__ float red[8];
    int b = blockIdx.x;
    int tid = threadIdx.x;
    int wave = tid >> 6, lane = tid & 63;
    int idx = b * 512 + tid;

    float ev = adj[idx] ? e[idx] : 0.f;
    float t = ev;
#pragma unroll
    for (int off = 32; off; off >>= 1) t += __shfl_xor(t, off);
    if (lane == 0) red[wave] = t;
    __syncthreads();
    float tot = red[0];
#pragma unroll
    for (int i = 1; i < 8; ++i) tot += red[i];
    float inv = 1.f / tot;
    w_out[idx] = ev * inv;

    const float* p = (tid < 256) ? p0 : p1;
    float* u = (tid < 256) ? u0 : u1;
    int h4 = tid & 255;
    float4 a = {0.f, 0.f, 0.f, 0.f};
#pragma unroll
    for (int s = 0; s < SLOTS; ++s) {
        float4 v = *(const float4*)(p + ((size_t)(s * 64 + b)) * HDIM + h4 * 4);
        a.x += v.x; a.y += v.y; a.z += v.z; a.w += v.w;
    }
    a.x *= inv; a.y *= inv; a.z *= inv; a.w *= inv;
    *(float4*)(u + (size_t)b * HDIM + h4 * 4) = a;
}

// ---------------- K3: split-k GEMM partials: pOut[kc][h][b] -----------------
// out[b][h] = sum_k u0[b][k]*Wr0[h][k] + u1[b][k]*Wr1[h][k]
// grid 256 blocks (ht*16+kc) x 256 threads. lane=b, wave owns 16 h rows.
__global__ __launch_bounds__(256) void k_out(const float* __restrict__ u0,
                                             const float* __restrict__ u1,
                                             const float* __restrict__ Wr0,
                                             const float* __restrict__ Wr1,
                                             float* __restrict__ pOut) {
    __shared__ float lds[64 * 128];
    int tid = threadIdx.x;
    int ht = blockIdx.x >> 4;
    int kc = blockIdx.x & 15;
    const float* usrc = (kc < 8) ? u0 : u1;
    const float* wsrc = (kc < 8) ? Wr0 : Wr1;
    int koff = (kc & 7) * 128;
    int h0 = ht * 64;

    {
        int c4 = tid & 31;
        int r2 = tid >> 5;
#pragma unroll
        for (int i = 0; i < 8; ++i) {
            int row = i * 8 + r2;
            float4 v = *(const float4*)(usrc + (size_t)row * HDIM + koff + c4 * 4);
            *(float4*)&lds[row * 128 + ((c4 ^ (row & 7)) << 2)] = v;
        }
    }
    __syncthreads();

    int b = tid & 63;
    int wu = __builtin_amdgcn_readfirstlane(tid >> 6);
    int hbase = h0 + wu * 16;
    const float* wrow = wsrc + (size_t)hbase * HDIM + koff;

    float acc[16];
#pragma unroll
    for (int j = 0; j < 16; ++j) acc[j] = 0.f;

#pragma unroll 4
    for (int k4 = 0; k4 < 32; ++k4) {
        float4 uv = *(float4*)&lds[b * 128 + ((k4 ^ (b & 7)) << 2)];
#pragma unroll
        for (int j = 0; j < 16; ++j) {
            float4 wv = *(const float4*)(wrow + (size_t)j * HDIM + k4 * 4);
            acc[j] = fmaf(uv.x, wv.x, acc[j]);
            acc[j] = fmaf(uv.y, wv.y, acc[j]);
            acc[j] = fmaf(uv.z, wv.z, acc[j]);
            acc[j] = fmaf(uv.w, wv.w, acc[j]);
        }
    }
#pragma unroll
    for (int j = 0; j < 16; ++j)
        pOut[((size_t)kc * HDIM + hbase + j) * 64 + b] = acc[j];
}

// ---------------- K4: reduce 16 k-chunks -> attn_sum[b][h] ------------------
// grid 256 blocks x 256 threads (4 h x 64 b per block).
__global__ __launch_bounds__(256) void k_redout(const float* __restrict__ pOut,
                                                float* __restrict__ out1) {
    int tid = threadIdx.x;
    int b = tid & 63;
    int h = blockIdx.x * 4 + (tid >> 6);
    float acc = 0.f;
#pragma unroll
    for (int kc = 0; kc < 16; ++kc)
        acc += pOut[((size_t)kc * HDIM + h) * 64 + b];
    out1[(size_t)b * HDIM + h] = acc;
}

extern "C" void kernel_launch(void* const* d_in, const int* in_sizes, int n_in,
                              void* d_out, int out_size, void* d_ws, size_t ws_size,
                              hipStream_t stream) {
    const float* Kmat  = (const float*)d_in[1];
    const float* V     = (const float*)d_in[2];
    const int*   adj   = (const int*)d_in[3];
    const int*   smask = (const int*)d_in[4];
    const int*   omask = (const int*)d_in[5];
    const float* Watt  = (const float*)d_in[6];
    const float* Wr0   = (const float*)d_in[8];
    const float* Wr1   = (const float*)d_in[9];
    float* out = (float*)d_out;
    float* ws  = (float*)d_ws;

    // ws layout (float offsets)
    float* e    = ws;                    //  64*512           = 32768
    float* p0   = ws + 32768;            //  SLOTS*64*1024    = 655360
    float* p1   = ws + 688128;           //  SLOTS*64*1024    = 655360
    float* u0   = ws + 1343488;          //  64*1024          = 65536
    float* u1   = ws + 1409024;          //  64*1024          = 65536
    float* pOut = ws + 1474560;          //  16*1024*64       = 1048576
    const float* Wk = Watt + HDIM;       // second half of W_att

    k_fusedA   <<<64 * SLOTS, 256, 0, stream>>>(Kmat, V, adj, smask, omask, Wk, e, p0, p1);
    k_denomredu<<<        64, 512, 0, stream>>>(e, adj, p0, p1, out, u0, u1);
    k_out      <<<       256, 256, 0, stream>>>(u0, u1, Wr0, Wr1, pOut);
    k_redout   <<<       256, 256, 0, stream>>>(pOut, out + 32768);
}

// Round 13
// 61.982 us; speedup vs baseline: 3.1156x; 1.0237x over previous
//
#include <hip/hip_runtime.h>
#include <math.h>

#define HDIM 1024
#define INVB (1 << 13)
#define SBIT (1 << 14)
#define OBIT (1 << 15)
#define SLOTS 5    // chunk = 64 compacted rows, capacity 320 adj-rows per b
#define CH 64

// ---------------- K1: self-compacting fused score+exp+V-weight --------------
// grid 64*SLOTS blocks x 256 threads; chunk = 64 compacted adj rows.
// Step 0: block redoes the adj ballot/prefix scan for its b (L2-hot),
//         extracts its own 64-row window (codes n|s<<14|o<<15), pads w/ INVB.
// Phase 1: 4 waves x 16 rows (8 pairs) -> e = exp(dot(K,Wk)); stage weights.
// Phase 2: wave 0 compacts (s|o)-active rows; stream those V rows 8-deep.
// NO cross-block atomics/fences (r9/r11 lesson: they cost 25x a launch).
__global__ __launch_bounds__(256) void k_fusedA(const float* __restrict__ Kmat,
                                                const float* __restrict__ V,
                                                const int* __restrict__ adj,
                                                const int* __restrict__ sm,
                                                const int* __restrict__ om,
                                                const float* __restrict__ Wk,
                                                float* __restrict__ e_out,
                                                float* __restrict__ p0,
                                                float* __restrict__ p1) {
    __shared__ int segc[8];
    __shared__ int codeL[CH];
    __shared__ float2 eso[CH];
    __shared__ float2 cw[CH + 8];
    __shared__ int cn[CH + 8];
    __shared__ int s_cnz8;
    int b = blockIdx.x / SLOTS;
    int chunk = blockIdx.x - b * SLOTS;
    int tid = threadIdx.x, wave = tid >> 6, lane = tid & 63;
    int gb = b * 512;
    int start = chunk * CH;
    size_t pbase = ((size_t)(chunk * 64 + b)) * HDIM + tid * 4;

    // ---- step 0: scan adj for this b, pick our window ----------------------
    int r0w = wave * 128;
    int a0p = adj[gb + r0w + lane] != 0;
    int a1p = adj[gb + r0w + 64 + lane] != 0;
    unsigned long long m0 = __ballot(a0p);
    unsigned long long m1 = __ballot(a1p);
    if (lane == 0) {
        segc[wave * 2]     = __popcll(m0);
        segc[wave * 2 + 1] = __popcll(m1);
    }
    __syncthreads();
    int tot = 0;
#pragma unroll
    for (int i = 0; i < 8; ++i) tot += segc[i];
    int kp = (tot + CH - 1) & ~(CH - 1);
    if (start >= kp) {                      // inactive slot: zero the partial
        float4 z = {0.f, 0.f, 0.f, 0.f};
        *(float4*)(p0 + pbase) = z;
        *(float4*)(p1 + pbase) = z;
        return;
    }
    {
        unsigned long long lt = (1ull << lane) - 1ull;
        int base = 0;
#pragma unroll
        for (int i = 0; i < 8; ++i) if (i < wave * 2) base += segc[i];
        int pos0 = base + __popcll(m0 & lt);
        if (a0p && pos0 >= start && pos0 < start + CH) {
            int r = r0w + lane;
            codeL[pos0 - start] = r | (sm[gb + r] ? SBIT : 0) | (om[gb + r] ? OBIT : 0);
        }
        int base1 = base + __popcll(m0);
        int pos1 = base1 + __popcll(m1 & lt);
        if (a1p && pos1 >= start && pos1 < start + CH) {
            int r = r0w + 64 + lane;
            codeL[pos1 - start] = r | (sm[gb + r] ? SBIT : 0) | (om[gb + r] ? OBIT : 0);
        }
    }
    if (tid < CH && start + tid >= tot) codeL[tid] = INVB;
    const float4* wk4 = (const float4*)Wk;
    float4 wk0 = wk4[lane], wk1 = wk4[64 + lane],
           wk2 = wk4[128 + lane], wk3 = wk4[192 + lane];
    __syncthreads();

    // ---- phase 1: 16 rows per wave, two at a time, 8 loads in flight -------
#pragma unroll
    for (int pp = 0; pp < 8; ++pp) {
        int rr = wave * 16 + pp * 2;
        int c0 = codeL[rr], c1 = codeL[rr + 1];
        int n0 = c0 & 511, n1 = c1 & 511;
        const float4* kq0 = (const float4*)(Kmat + (size_t)(gb + n0) * HDIM);
        const float4* kq1 = (const float4*)(Kmat + (size_t)(gb + n1) * HDIM);
        float4 a0 = kq0[lane],       a1 = kq0[64 + lane],
               a2 = kq0[128 + lane], a3 = kq0[192 + lane];
        float4 d0 = kq1[lane],       d1 = kq1[64 + lane],
               d2 = kq1[128 + lane], d3 = kq1[192 + lane];
        __builtin_amdgcn_sched_barrier(0);

        float s0 = 0.f, s1 = 0.f;
        s0 = fmaf(a0.x, wk0.x, s0); s0 = fmaf(a0.y, wk0.y, s0);
        s0 = fmaf(a0.z, wk0.z, s0); s0 = fmaf(a0.w, wk0.w, s0);
        s0 = fmaf(a1.x, wk1.x, s0); s0 = fmaf(a1.y, wk1.y, s0);
        s0 = fmaf(a1.z, wk1.z, s0); s0 = fmaf(a1.w, wk1.w, s0);
        s0 = fmaf(a2.x, wk2.x, s0); s0 = fmaf(a2.y, wk2.y, s0);
        s0 = fmaf(a2.z, wk2.z, s0); s0 = fmaf(a2.w, wk2.w, s0);
        s0 = fmaf(a3.x, wk3.x, s0); s0 = fmaf(a3.y, wk3.y, s0);
        s0 = fmaf(a3.z, wk3.z, s0); s0 = fmaf(a3.w, wk3.w, s0);
        s1 = fmaf(d0.x, wk0.x, s1); s1 = fmaf(d0.y, wk0.y, s1);
        s1 = fmaf(d0.z, wk0.z, s1); s1 = fmaf(d0.w, wk0.w, s1);
        s1 = fmaf(d1.x, wk1.x, s1); s1 = fmaf(d1.y, wk1.y, s1);
        s1 = fmaf(d1.z, wk1.z, s1); s1 = fmaf(d1.w, wk1.w, s1);
        s1 = fmaf(d2.x, wk2.x, s1); s1 = fmaf(d2.y, wk2.y, s1);
        s1 = fmaf(d2.z, wk2.z, s1); s1 = fmaf(d2.w, wk2.w, s1);
        s1 = fmaf(d3.x, wk3.x, s1); s1 = fmaf(d3.y, wk3.y, s1);
        s1 = fmaf(d3.z, wk3.z, s1); s1 = fmaf(d3.w, wk3.w, s1);

#pragma unroll
        for (int off = 32; off; off >>= 1) {
            s0 += __shfl_xor(s0, off);
            s1 += __shfl_xor(s1, off);
        }
        if (lane == 0) {
            float e0 = expf(s0), e1 = expf(s1);
            if (!(c0 & INVB)) e_out[gb + n0] = e0;
            if (!(c1 & INVB)) e_out[gb + n1] = e1;
            eso[rr]     = make_float2((c0 & SBIT) ? e0 : 0.f, (c0 & OBIT) ? e0 : 0.f);
            eso[rr + 1] = make_float2((c1 & SBIT) ? e1 : 0.f, (c1 & OBIT) ? e1 : 0.f);
        }
    }
    __syncthreads();

    // ---- compaction of (s|o)-active rows by wave 0 (64-wide window) --------
    if (wave == 0) {
        int code = codeL[lane];
        bool pred = ((code & (SBIT | OBIT)) != 0) && !(code & INVB);
        unsigned long long m = __ballot(pred);
        int cnz = __popcll(m);
        if (pred) {
            int pos = __popcll(m & ((1ull << lane) - 1ull));
            cn[pos] = code & 511;
            cw[pos] = eso[lane];
        }
        int cnz8 = (cnz + 7) & ~7;
        if (lane < 8) {                      // pad (disjoint from pos<cnz writes)
            int p = cnz + lane;
            if (p < cnz8) { cn[p] = 0; cw[p] = make_float2(0.f, 0.f); }
        }
        if (lane == 0) s_cnz8 = cnz8;
    }
    __syncthreads();

    // ---- phase 2: V-weight active rows, 8-deep batches ---------------------
    int cnz8 = s_cnz8;
    const float* Vb = V + (size_t)gb * HDIM;
    float4 a0 = {0.f, 0.f, 0.f, 0.f};
    float4 a1 = {0.f, 0.f, 0.f, 0.f};
    for (int g = 0; g < cnz8; g += 8) {
        int nn[8]; float2 ww[8];
#pragma unroll
        for (int i = 0; i < 8; ++i) { nn[i] = cn[g + i]; ww[i] = cw[g + i]; }
        float4 v[8];
#pragma unroll
        for (int i = 0; i < 8; ++i)
            v[i] = *((const float4*)(Vb + (size_t)nn[i] * HDIM) + tid);
        __builtin_amdgcn_sched_barrier(0);
#pragma unroll
        for (int i = 0; i < 8; ++i) {
            a0.x = fmaf(ww[i].x, v[i].x, a0.x); a0.y = fmaf(ww[i].x, v[i].y, a0.y);
            a0.z = fmaf(ww[i].x, v[i].z, a0.z); a0.w = fmaf(ww[i].x, v[i].w, a0.w);
            a1.x = fmaf(ww[i].y, v[i].x, a1.x); a1.y = fmaf(ww[i].y, v[i].y, a1.y);
            a1.z = fmaf(ww[i].y, v[i].z, a1.z); a1.w = fmaf(ww[i].y, v[i].w, a1.w);
        }
    }
    *(float4*)(p0 + pbase) = a0;
    *(float4*)(p1 + pbase) = a1;
}

// ---------------- K2: denom + attn_weight + u reduce+normalize --------------
// grid 64 blocks (per b) x 512 threads.
__global__ __launch_bounds__(512) void k_denomredu(const float* __restrict__ e,
                                                   const int* __restrict__ adj,
                                                   const float* __restrict__ p0,
                                                   const float* __restrict__ p1,
                                                   float* __restrict__ w_out,
                                                   float* __restrict__ u0,
                                                   float* __restrict__ u1) {
    __shared__ float red[8];
    int b = blockIdx.x;
    int tid = threadIdx.x;
    int wave = tid >> 6, lane = tid & 63;
    int idx = b * 512 + tid;

    float ev = adj[idx] ? e[idx] : 0.f;
    float t = ev;
#pragma unroll
    for (int off = 32; off; off >>= 1) t += __shfl_xor(t, off);
    if (lane == 0) red[wave] = t;
    __syncthreads();
    float tot = red[0];
#pragma unroll
    for (int i = 1; i < 8; ++i) tot += red[i];
    float inv = 1.f / tot;
    w_out[idx] = ev * inv;

    const float* p = (tid < 256) ? p0 : p1;
    float* u = (tid < 256) ? u0 : u1;
    int h4 = tid & 255;
    float4 a = {0.f, 0.f, 0.f, 0.f};
#pragma unroll
    for (int s = 0; s < SLOTS; ++s) {
        float4 v = *(const float4*)(p + ((size_t)(s * 64 + b)) * HDIM + h4 * 4);
        a.x += v.x; a.y += v.y; a.z += v.z; a.w += v.w;
    }
    a.x *= inv; a.y *= inv; a.z *= inv; a.w *= inv;
    *(float4*)(u + (size_t)b * HDIM + h4 * 4) = a;
}

// ---------------- K3: split-k GEMM partials: pOut[kc][h][b] -----------------
// out[b][h] = sum_k u0[b][k]*Wr0[h][k] + u1[b][k]*Wr1[h][k]
// grid 256 blocks (ht*16+kc) x 256 threads. lane=b, wave owns 16 h rows.
__global__ __launch_bounds__(256) void k_out(const float* __restrict__ u0,
                                             const float* __restrict__ u1,
                                             const float* __restrict__ Wr0,
                                             const float* __restrict__ Wr1,
                                             float* __restrict__ pOut) {
    __shared__ float lds[64 * 128];
    int tid = threadIdx.x;
    int ht = blockIdx.x >> 4;
    int kc = blockIdx.x & 15;
    const float* usrc = (kc < 8) ? u0 : u1;
    const float* wsrc = (kc < 8) ? Wr0 : Wr1;
    int koff = (kc & 7) * 128;
    int h0 = ht * 64;

    {
        int c4 = tid & 31;
        int r2 = tid >> 5;
#pragma unroll
        for (int i = 0; i < 8; ++i) {
            int row = i * 8 + r2;
            float4 v = *(const float4*)(usrc + (size_t)row * HDIM + koff + c4 * 4);
            *(float4*)&lds[row * 128 + ((c4 ^ (row & 7)) << 2)] = v;
        }
    }
    __syncthreads();

    int b = tid & 63;
    int wu = __builtin_amdgcn_readfirstlane(tid >> 6);
    int hbase = h0 + wu * 16;
    const float* wrow = wsrc + (size_t)hbase * HDIM + koff;

    float acc[16];
#pragma unroll
    for (int j = 0; j < 16; ++j) acc[j] = 0.f;

#pragma unroll 4
    for (int k4 = 0; k4 < 32; ++k4) {
        float4 uv = *(float4*)&lds[b * 128 + ((k4 ^ (b & 7)) << 2)];
#pragma unroll
        for (int j = 0; j < 16; ++j) {
            float4 wv = *(const float4*)(wrow + (size_t)j * HDIM + k4 * 4);
            acc[j] = fmaf(uv.x, wv.x, acc[j]);
            acc[j] = fmaf(uv.y, wv.y, acc[j]);
            acc[j] = fmaf(uv.z, wv.z, acc[j]);
            acc[j] = fmaf(uv.w, wv.w, acc[j]);
        }
    }
#pragma unroll
    for (int j = 0; j < 16; ++j)
        pOut[((size_t)kc * HDIM + hbase + j) * 64 + b] = acc[j];
}

// ---------------- K4: reduce 16 k-chunks -> attn_sum[b][h] ------------------
// grid 256 blocks x 256 threads (4 h x 64 b per block).
__global__ __launch_bounds__(256) void k_redout(const float* __restrict__ pOut,
                                                float* __restrict__ out1) {
    int tid = threadIdx.x;
    int b = tid & 63;
    int h = blockIdx.x * 4 + (tid >> 6);
    float acc = 0.f;
#pragma unroll
    for (int kc = 0; kc < 16; ++kc)
        acc += pOut[((size_t)kc * HDIM + h) * 64 + b];
    out1[(size_t)b * HDIM + h] = acc;
}

extern "C" void kernel_launch(void* const* d_in, const int* in_sizes, int n_in,
                              void* d_out, int out_size, void* d_ws, size_t ws_size,
                              hipStream_t stream) {
    const float* Kmat  = (const float*)d_in[1];
    const float* V     = (const float*)d_in[2];
    const int*   adj   = (const int*)d_in[3];
    const int*   smask = (const int*)d_in[4];
    const int*   omask = (const int*)d_in[5];
    const float* Watt  = (const float*)d_in[6];
    const float* Wr0   = (const float*)d_in[8];
    const float* Wr1   = (const float*)d_in[9];
    float* out = (float*)d_out;
    float* ws  = (float*)d_ws;

    // ws layout (float offsets)
    float* e    = ws;                    //  64*512           = 32768
    float* p0   = ws + 32768;            //  SLOTS*64*1024    = 327680
    float* p1   = ws + 360448;           //  SLOTS*64*1024    = 327680
    float* u0   = ws + 688128;           //  64*1024          = 65536
    float* u1   = ws + 753664;           //  64*1024          = 65536
    float* pOut = ws + 819200;           //  16*1024*64       = 1048576
    const float* Wk = Watt + HDIM;       // second half of W_att

    k_fusedA   <<<64 * SLOTS, 256, 0, stream>>>(Kmat, V, adj, smask, omask, Wk, e, p0, p1);
    k_denomredu<<<        64, 512, 0, stream>>>(e, adj, p0, p1, out, u0, u1);
    k_out      <<<       256, 256, 0, stream>>>(u0, u1, Wr0, Wr1, pOut);
    k_redout   <<<       256, 256, 0, stream>>>(pOut, out + 32768);
}